// Round 14
// baseline (169.801 us; speedup 1.0000x reference)
//
#include <hip/hip_runtime.h>
#include <hip/hip_bf16.h>

#define HID 128
#define NGRAPH 512

typedef __attribute__((ext_vector_type(8))) short short8;   // 8 bf16 (4 VGPR)
typedef __attribute__((ext_vector_type(4))) float f32x4;    // MFMA acc

// bf16 helpers (RNE)
__device__ inline unsigned int f2bf(float f) {
    unsigned int u = __float_as_uint(f);
    return (u + 0x7FFFu + ((u >> 16) & 1u)) >> 16;
}
__device__ inline float bflo(unsigned int w) { return __uint_as_float(w << 16); }
__device__ inline float bfhi(unsigned int w) { return __uint_as_float(w & 0xFFFF0000u); }

// ---------------------------------------------------------------------------
// Setup kernel 1: zero deg  +  foldW (W4p,b4p)  +  bf16-transpose W2/W3.
// 1024 threads; blocks 0..nzb-1 zero, block nzb = foldW, nzb+1/nzb+2 = casts.
// ---------------------------------------------------------------------------

__device__ inline void wcast_body(const float* __restrict__ W,
                                  unsigned short* __restrict__ Wt) {
    int t = threadIdx.x;   // 1024 threads
#pragma unroll
    for (int i = 0; i < 16; ++i) {
        int flat = i * 1024 + t;
        int n = flat >> 7, k = flat & 127;
        Wt[n * HID + k] = (unsigned short)f2bf(W[k * HID + n]);
    }
}

__global__ void k_setup1(int* __restrict__ deg, int n, int nzb,
                         const float* __restrict__ W4, const float* __restrict__ linW,
                         const float* __restrict__ b4, const float* __restrict__ linb,
                         float* __restrict__ W4p, float* __restrict__ b4p,
                         const float* __restrict__ W2, const float* __restrict__ W3,
                         unsigned short* __restrict__ Wt2, unsigned short* __restrict__ Wt3) {
    if ((int)blockIdx.x == nzb) {
        int idx = threadIdx.x;
        if (idx < 256) {
            int k = idx >> 1, c = idx & 1;
            float a = 0.0f;
            for (int j = 0; j < HID; ++j) a = fmaf(W4[k * HID + j], linW[j * 2 + c], a);
            W4p[idx] = a;
            if (idx < 2) {
                float b = 0.0f;
                for (int j = 0; j < HID; ++j) b = fmaf(b4[j], linW[j * 2 + idx], b);
                b4p[idx] = b + linb[idx];
            }
        }
        return;
    }
    if ((int)blockIdx.x == nzb + 1) { wcast_body(W2, Wt2); return; }
    if ((int)blockIdx.x == nzb + 2) { wcast_body(W3, Wt3); return; }
    int i = blockIdx.x * 1024 + threadIdx.x;
    if (i < n) deg[i] = 0;
}

// degree count; records each edge's position within its dst bucket
__global__ void k_count(const int* __restrict__ ei, int* __restrict__ deg,
                        int* __restrict__ epos, int E) {
    int e = blockIdx.x * blockDim.x + threadIdx.x;
    if (e < E) epos[e] = atomicAdd(&deg[ei[E + e]], 1);
}

// ---------------------------------------------------------------------------
// Fused scan: each block sums deg[0..blockStart) itself (no bsum kernel),
// then wave-scans its 1024 chunk -> row_start; also dinv + pre-scaled Xs.
// ---------------------------------------------------------------------------
__global__ void k_scan2b(const int* __restrict__ deg, int* __restrict__ row_start,
                         float* __restrict__ dinv, const float* __restrict__ x,
                         float* __restrict__ Xs, int n, int nblocks) {
    __shared__ int rs[16];
    __shared__ int ws[16];
    __shared__ int s_off_sh;
    int lane = threadIdx.x & 63, wid = threadIdx.x >> 6;
    // phase A: offset = sum deg[0 .. blockIdx*1024)
    {
        int before = blockIdx.x * 1024;
        int p = 0;
        for (int i = threadIdx.x; i < before; i += 1024) p += deg[i];
#pragma unroll
        for (int off = 32; off; off >>= 1) p += __shfl_down(p, off);
        if (lane == 0) rs[wid] = p;
        __syncthreads();
        if (threadIdx.x == 0) {
            int s = 0;
#pragma unroll
            for (int w = 0; w < 16; ++w) s += rs[w];
            s_off_sh = s;
        }
        __syncthreads();
    }
    // phase B: per-element dinv/Xs + block-local scan
    int i = blockIdx.x * 1024 + threadIdx.x;
    int v = (i < n) ? deg[i] : 0;
    if (i < n) {
        float dv = rsqrtf((float)v + 1.0f);
        dinv[i] = dv;
        float4 r;
        r.x = x[i * 3 + 0] * dv;
        r.y = x[i * 3 + 1] * dv;
        r.z = x[i * 3 + 2] * dv;
        r.w = 0.0f;
        *(float4*)&Xs[i * 4] = r;
    }
    int xx = v;
#pragma unroll
    for (int off = 1; off < 64; off <<= 1) {
        int t = __shfl_up(xx, off);
        if (lane >= off) xx += t;
    }
    if (lane == 63) ws[wid] = xx;
    __syncthreads();
    int wo = 0;
    for (int w = 0; w < wid; ++w) wo += ws[w];
    int excl = s_off_sh + wo + xx - v;
    if (i < n) row_start[i] = excl;
    if ((int)blockIdx.x == nblocks - 1 && threadIdx.x == 0) {
        int ct = 0;
#pragma unroll
        for (int w = 0; w < 16; ++w) ct += ws[w];
        row_start[n] = s_off_sh + ct;
    }
}

// atomic-free fill using saved positions
__global__ void k_fill(const int* __restrict__ ei, const int* __restrict__ row_start,
                       const int* __restrict__ epos, int* __restrict__ src_sorted, int E) {
    int e = blockIdx.x * blockDim.x + threadIdx.x;
    if (e < E) {
        int s = ei[e];
        int d = ei[E + e];
        src_sorted[row_start[d] + epos[e]] = s;
    }
}

// ---------------------------------------------------------------------------
// Fused layer 1: per block of 32 nodes, gather Xs (8 lanes/node) into LDS,
// then Act16 = bf16(relu(xa . W1 + b1)) directly.  Zero for padding rows.
// ---------------------------------------------------------------------------
__global__ __launch_bounds__(256) void k_l1(const float* __restrict__ Xs,
                                            const int* __restrict__ row_start,
                                            const int* __restrict__ src_sorted,
                                            const float* __restrict__ dinv,
                                            const float* __restrict__ W1,
                                            const float* __restrict__ b1,
                                            unsigned int* __restrict__ Act16, int n) {
    __shared__ float xs[32][4];
    int v0 = blockIdx.x * 32;
    int vl0 = threadIdx.x >> 3, sub = threadIdx.x & 7;
    int v = v0 + vl0;
    float a0 = 0.f, a1 = 0.f, a2 = 0.f;
    if (v < n) {
        int e0 = row_start[v], e1 = row_start[v + 1];
        for (int e = e0 + sub; e < e1; e += 8) {
            int s = src_sorted[e];
            float4 xv = *(const float4*)&Xs[s * 4];
            a0 += xv.x; a1 += xv.y; a2 += xv.z;
        }
    }
#pragma unroll
    for (int off = 4; off; off >>= 1) {
        a0 += __shfl_down(a0, off);
        a1 += __shfl_down(a1, off);
        a2 += __shfl_down(a2, off);
    }
    if (sub == 0 && v < n) {
        float dv = dinv[v];
        float4 xv = *(const float4*)&Xs[v * 4];
        xs[vl0][0] = (a0 + xv.x) * dv;
        xs[vl0][1] = (a1 + xv.y) * dv;
        xs[vl0][2] = (a2 + xv.z) * dv;
    }
    __syncthreads();
    // feat phase: 32 nodes x 64 col-pairs = 2048 outputs, contiguous
    unsigned int base = (unsigned int)v0 * 64;
#pragma unroll
    for (int i = 0; i < 8; ++i) {
        int flat = i * 256 + threadIdx.x;
        int vl = flat >> 6, cp = flat & 63;
        unsigned int w = 0;
        if (v0 + vl < n) {
            float x0 = xs[vl][0], x1 = xs[vl][1], x2 = xs[vl][2];
            int c0 = cp * 2, c1 = c0 + 1;
            float r0 = fmaf(x0, W1[c0], fmaf(x1, W1[HID + c0], fmaf(x2, W1[2 * HID + c0], b1[c0])));
            float r1 = fmaf(x0, W1[c1], fmaf(x1, W1[HID + c1], fmaf(x2, W1[2 * HID + c1], b1[c1])));
            w = f2bf(fmaxf(r0, 0.f)) | (f2bf(fmaxf(r1, 0.f)) << 16);
        }
        Act16[base + flat] = w;
    }
}

// ---------------------------------------------------------------------------
// MFMA GEMM: bf16 X[Npad,128] @ Wt (bf16, [n][k]) -> bf16 H, row-scaled by dinv.
// Block = 64 rows, 4 waves; wave = 1 M-tile x 8 N-tiles x 4 K-steps of
// v_mfma_f32_16x16x32_bf16.  Wt in LDS with XOR swizzle; C bounced via LDS.
// ---------------------------------------------------------------------------
__global__ __launch_bounds__(256) void k_gemm_mfma(const unsigned short* __restrict__ X,
                                                   const unsigned short* __restrict__ Wtg,
                                                   const float* __restrict__ dinv,
                                                   unsigned short* __restrict__ Hout) {
    __shared__ unsigned short Wt[HID * HID];   // 32 KB
    {
        int nrow = threadIdx.x >> 1, s = threadIdx.x & 1;
        int xr = (nrow & 7) << 3;              // XOR swizzle, bf16-chunk units
#pragma unroll
        for (int i = 0; i < 8; ++i) {
            int b16 = s * 64 + i * 8;          // chunk base within row
            uint4 src = *(const uint4*)&Wtg[nrow * HID + b16];
            *(uint4*)&Wt[nrow * HID + (b16 ^ xr)] = src;
        }
    }
    __syncthreads();

    int w    = threadIdx.x >> 6;               // wave -> M-tile
    int lane = threadIdx.x & 63;
    int g    = lane >> 4;                      // k-group (0..3)
    int mr   = lane & 15;                      // m (A) / n (B) index
    size_t row0 = (size_t)blockIdx.x * 64;
    size_t arow = row0 + w * 16 + mr;

    short8 a[4];
#pragma unroll
    for (int ks = 0; ks < 4; ++ks)
        a[ks] = *(const short8*)&X[arow * HID + ks * 32 + g * 8];

    f32x4 acc[8];
#pragma unroll
    for (int nt = 0; nt < 8; ++nt) acc[nt] = (f32x4){0.f, 0.f, 0.f, 0.f};

#pragma unroll
    for (int nt = 0; nt < 8; ++nt) {
        int nrow = nt * 16 + mr;
        int xr = (nrow & 7) << 3;
        short8 b[4];
#pragma unroll
        for (int ks = 0; ks < 4; ++ks)
            b[ks] = *(const short8*)&Wt[nrow * HID + ((ks * 32 + g * 8) ^ xr)];
#pragma unroll
        for (int ks = 0; ks < 4; ++ks)
            acc[nt] = __builtin_amdgcn_mfma_f32_16x16x32_bf16(a[ks], b[ks], acc[nt], 0, 0, 0);
    }

    // Epilogue: C/D map col = lane&15, row = g*4 + reg (m89).  Scale + LDS bounce.
    __syncthreads();                           // Wt reads done; reuse as C tile [64][128]
    {
        int rrb = w * 16 + g * 4;
#pragma unroll
        for (int j = 0; j < 4; ++j) {
            int rr = rrb + j;
            float dv = dinv[row0 + rr];
#pragma unroll
            for (int nt = 0; nt < 8; ++nt) {
                int col = nt * 16 + mr;
                int idx = rr * HID + ((col & 7) | ((((col >> 3)) ^ (rr & 7)) << 3));
                Wt[idx] = (unsigned short)f2bf(acc[nt][j] * dv);
            }
        }
    }
    __syncthreads();
    {
        int rr = threadIdx.x >> 2, s = threadIdx.x & 3;
        int xr = (rr & 7) << 3;
#pragma unroll
        for (int i = 0; i < 4; ++i) {
            int b16 = s * 32 + i * 8;
            uint4 v = *(const uint4*)&Wt[rr * HID + (b16 ^ xr)];
            *(uint4*)&Hout[(row0 + rr) * HID + b16] = v;
        }
    }
}

// ---------------------------------------------------------------------------
// Fused aggregation on pre-scaled bf16 rows: Act16 = bf16(relu(dv*(sum+self)+b)).
// 2 nodes per wave; lane = 4 cols (uint2 = 4 bf16, 8 B); f32 accumulate.
// ---------------------------------------------------------------------------
__global__ __launch_bounds__(256) void k_gather(const unsigned short* __restrict__ Hs,
                                                const int* __restrict__ row_start,
                                                const int* __restrict__ src_sorted,
                                                const float* __restrict__ dinv,
                                                const float* __restrict__ bias,
                                                unsigned short* __restrict__ Aout, int n) {
    int wid  = (blockIdx.x * blockDim.x + threadIdx.x) >> 6;
    int lane = threadIdx.x & 63;
    int half = lane >> 5, hl = lane & 31;
    int v0 = wid * 2;
    if (v0 >= n) return;
    int v  = v0 + half;
    bool real = (v < n);
    int vc = real ? v : v0;
    int e0 = row_start[vc];
    int e1 = row_start[vc + 1];
    int deg = e1 - e0;
    int myidx = (hl < deg) ? src_sorted[e0 + hl] : vc;
    float4 acc = make_float4(0.f, 0.f, 0.f, 0.f);
    int dcap = (deg < 32) ? deg : 32;
    for (int base = 0; base < dcap; base += 16) {
        uint2 h[16];
        float m[16];
#pragma unroll
        for (int j = 0; j < 16; ++j) {
            int ej = base + j;
            int sj = __shfl(myidx, (half << 5) | ej);
            m[j] = (ej < deg) ? 1.0f : 0.0f;
            h[j] = *(const uint2*)&Hs[(size_t)sj * HID + hl * 4];
        }
#pragma unroll
        for (int j = 0; j < 16; ++j) {
            acc.x = fmaf(bflo(h[j].x), m[j], acc.x);
            acc.y = fmaf(bfhi(h[j].x), m[j], acc.y);
            acc.z = fmaf(bflo(h[j].y), m[j], acc.z);
            acc.w = fmaf(bfhi(h[j].y), m[j], acc.w);
        }
    }
    // rare tail: deg > 32
    for (int e = e0 + 32; e < e1; ++e) {
        int sj = src_sorted[e];
        uint2 h = *(const uint2*)&Hs[(size_t)sj * HID + hl * 4];
        acc.x += bflo(h.x); acc.y += bfhi(h.x);
        acc.z += bflo(h.y); acc.w += bfhi(h.y);
    }
    float dv = dinv[vc];
    uint2 sv = *(const uint2*)&Hs[(size_t)vc * HID + hl * 4];
    float4 bb = *(const float4*)&bias[hl * 4];
    float ox = fmaxf(fmaf(acc.x + bflo(sv.x), dv, bb.x), 0.0f);
    float oy = fmaxf(fmaf(acc.y + bfhi(sv.x), dv, bb.y), 0.0f);
    float oz = fmaxf(fmaf(acc.z + bflo(sv.y), dv, bb.z), 0.0f);
    float ow = fmaxf(fmaf(acc.w + bfhi(sv.y), dv, bb.w), 0.0f);
    if (real) {
        uint2 o2;
        o2.x = f2bf(ox) | (f2bf(oy) << 16);
        o2.y = f2bf(oz) | (f2bf(ow) << 16);
        *(uint2*)&Aout[(size_t)v * HID + hl * 4] = o2;
    }
}

// Layer-3 variant: bf16 gather + bias + relu, project onto W4p [128,2],
// store P3s[v] = (proj)*dinv[v].
__global__ __launch_bounds__(256) void k_gather_proj(const unsigned short* __restrict__ Hs,
                                                     const int* __restrict__ row_start,
                                                     const int* __restrict__ src_sorted,
                                                     const float* __restrict__ dinv,
                                                     const float* __restrict__ bias,
                                                     const float* __restrict__ W4p,
                                                     float* __restrict__ P3s, int n) {
    int wid  = (blockIdx.x * blockDim.x + threadIdx.x) >> 6;
    int lane = threadIdx.x & 63;
    int half = lane >> 5, hl = lane & 31;
    int v0 = wid * 2;
    if (v0 >= n) return;
    int v  = v0 + half;
    bool real = (v < n);
    int vc = real ? v : v0;
    int e0 = row_start[vc];
    int e1 = row_start[vc + 1];
    int deg = e1 - e0;
    int myidx = (hl < deg) ? src_sorted[e0 + hl] : vc;
    float4 acc = make_float4(0.f, 0.f, 0.f, 0.f);
    int dcap = (deg < 32) ? deg : 32;
    for (int base = 0; base < dcap; base += 16) {
        uint2 h[16];
        float m[16];
#pragma unroll
        for (int j = 0; j < 16; ++j) {
            int ej = base + j;
            int sj = __shfl(myidx, (half << 5) | ej);
            m[j] = (ej < deg) ? 1.0f : 0.0f;
            h[j] = *(const uint2*)&Hs[(size_t)sj * HID + hl * 4];
        }
#pragma unroll
        for (int j = 0; j < 16; ++j) {
            acc.x = fmaf(bflo(h[j].x), m[j], acc.x);
            acc.y = fmaf(bfhi(h[j].x), m[j], acc.y);
            acc.z = fmaf(bflo(h[j].y), m[j], acc.z);
            acc.w = fmaf(bfhi(h[j].y), m[j], acc.w);
        }
    }
    for (int e = e0 + 32; e < e1; ++e) {
        int sj = src_sorted[e];
        uint2 h = *(const uint2*)&Hs[(size_t)sj * HID + hl * 4];
        acc.x += bflo(h.x); acc.y += bfhi(h.x);
        acc.z += bflo(h.y); acc.w += bfhi(h.y);
    }
    float dv = dinv[vc];
    uint2 sv = *(const uint2*)&Hs[(size_t)vc * HID + hl * 4];
    float4 bb = *(const float4*)&bias[hl * 4];
    float ox = fmaxf(fmaf(acc.x + bflo(sv.x), dv, bb.x), 0.0f);
    float oy = fmaxf(fmaf(acc.y + bfhi(sv.x), dv, bb.y), 0.0f);
    float oz = fmaxf(fmaf(acc.z + bflo(sv.y), dv, bb.z), 0.0f);
    float ow = fmaxf(fmaf(acc.w + bfhi(sv.y), dv, bb.w), 0.0f);
    // project the lane's 4 cols (k = 4*hl .. 4*hl+3) onto W4p [k][2]
    float4 wA = *(const float4*)&W4p[hl * 8 + 0];
    float4 wB = *(const float4*)&W4p[hl * 8 + 4];
    float p0 = ox * wA.x + oy * wA.z + oz * wB.x + ow * wB.z;
    float p1 = ox * wA.y + oy * wA.w + oz * wB.y + ow * wB.w;
#pragma unroll
    for (int off = 16; off; off >>= 1) {
        p0 += __shfl_down(p0, off);
        p1 += __shfl_down(p1, off);
    }
    if (hl == 0 && real) *(float2*)&P3s[v * 2] = make_float2(p0 * dv, p1 * dv);
}

// ---------------------------------------------------------------------------
// Fused tail: block per graph.  Layer-4 2-wide gather (8 lanes/node) and
// mean-pool + head bias, all in one kernel.  No atomics, no A2 buffer.
// ---------------------------------------------------------------------------
__global__ __launch_bounds__(256) void k_tail(const float* __restrict__ P3s,
                                              const int* __restrict__ row_start,
                                              const int* __restrict__ src_sorted,
                                              const float* __restrict__ dinv,
                                              const int* __restrict__ batch,
                                              const float* __restrict__ b4p,
                                              float* __restrict__ out, int n) {
    int g = blockIdx.x;
    // span of graph g in sorted batch
    int lo = 0, hi = n;
    while (lo < hi) { int m = (lo + hi) >> 1; if (batch[m] < g) lo = m + 1; else hi = m; }
    int start = lo;
    hi = n;
    while (lo < hi) { int m = (lo + hi) >> 1; if (batch[m] < g + 1) lo = m + 1; else hi = m; }
    int end = lo;

    int grp = threadIdx.x >> 3, sub = threadIdx.x & 7;   // 32 groups x 8 lanes
    float gx = 0.f, gy = 0.f;
    for (int v = start + grp; v < end; v += 32) {
        float ax = 0.f, ay = 0.f;
        int e0 = row_start[v], e1 = row_start[v + 1];
        for (int e = e0 + sub; e < e1; e += 8) {
            int s = src_sorted[e];
            float2 ps = *(const float2*)&P3s[s * 2];
            ax += ps.x;
            ay += ps.y;
        }
#pragma unroll
        for (int off = 4; off; off >>= 1) {
            ax += __shfl_down(ax, off);
            ay += __shfl_down(ay, off);
        }
        if (sub == 0) {
            float dv = dinv[v];
            float2 pv = *(const float2*)&P3s[v * 2];
            gx += (ax + pv.x) * dv;
            gy += (ay + pv.y) * dv;
        }
    }
    __shared__ float red[64];
    if (sub == 0) { red[grp] = gx; red[grp + 32] = gy; }
    __syncthreads();
    if (threadIdx.x < 64) {
        float sx = (threadIdx.x < 32) ? red[threadIdx.x] : 0.f;
        float sy = (threadIdx.x < 32) ? red[threadIdx.x + 32] : 0.f;
#pragma unroll
        for (int off = 16; off; off >>= 1) {
            sx += __shfl_down(sx, off);
            sy += __shfl_down(sy, off);
        }
        if (threadIdx.x == 0) {
            float inv = 1.0f / fmaxf((float)(end - start), 1.0f);
            out[g * 2 + 0] = sx * inv + b4p[0];
            out[g * 2 + 1] = sy * inv + b4p[1];
        }
    }
}

// ---------------------------------------------------------------------------

extern "C" void kernel_launch(void* const* d_in, const int* in_sizes, int n_in,
                              void* d_out, int out_size, void* d_ws, size_t ws_size,
                              hipStream_t stream) {
    const float* x    = (const float*)d_in[0];
    const float* W1   = (const float*)d_in[1];
    const float* b1   = (const float*)d_in[2];
    const float* W2   = (const float*)d_in[3];
    const float* b2   = (const float*)d_in[4];
    const float* W3   = (const float*)d_in[5];
    const float* b3   = (const float*)d_in[6];
    const float* W4   = (const float*)d_in[7];
    const float* b4   = (const float*)d_in[8];
    const float* linW = (const float*)d_in[9];
    const float* linb = (const float*)d_in[10];
    const int*   ei   = (const int*)d_in[11];   // [2,E]
    const int*   batch= (const int*)d_in[12];   // [N]
    float* out        = (float*)d_out;

    const int N = in_sizes[0] / 3;
    const int E = in_sizes[11] / 2;
    const int NPAD = ((N + 127) / 128) * 128;   // 64 | NPAD for MFMA blocks
    const int NB1024 = (N + 1023) / 1024;

    // Workspace layout (4-B slots)
    float* ws = (float*)d_ws;
    float* dinv       = ws;                             // 50176
    int*   deg_i      = (int*)(ws + 50176);             // 50176
    int*   row_start  = (int*)(ws + 100352);            // 50432 (N+1)
    int*   epos       = (int*)(ws + 150784);            // 600064
    int*   bsum       = (int*)(ws + 750848);            // 64 (unused now)
    float* W4p        = ws + 750912;                    // 256
    float* b4p        = ws + 751168;                    // 64 (2 used)
    int*   src_sorted = (int*)(ws + 751232);            // 600064
    float* P3s        = ws + 1552000;                   // N*2 (pad 100352)
    unsigned short* Hbuf16 = (unsigned short*)(ws + 1652352);  // NPAD*128 bf16
    float* Xs         = ws + 1652352;                   // N*4 f32 (aliases Hbuf16;
                                                        //  dead before gemm writes)
    unsigned short* Act16 = (unsigned short*)(ws + 1652352 + (size_t)NPAD * 64);
    unsigned short* Wt2g  = (unsigned short*)(ws + 1652352 + 2 * (size_t)NPAD * 64);
    unsigned short* Wt3g  = Wt2g + HID * HID;           // 16384 bf16 each
    (void)bsum;

    const int B = 256;

    // --- Setup: {zero deg | foldW | W2,W3 casts} -> count -> scan -> fill ---
    k_setup1<<<NB1024 + 3, 1024, 0, stream>>>(deg_i, N, NB1024, W4, linW, b4, linb,
                                              W4p, b4p, W2, W3, Wt2g, Wt3g);
    k_count<<<(E + B - 1) / B, B, 0, stream>>>(ei, deg_i, epos, E);
    k_scan2b<<<NB1024, 1024, 0, stream>>>(deg_i, row_start, dinv, x, Xs, N, NB1024);
    k_fill<<<(E + B - 1) / B, B, 0, stream>>>(ei, row_start, epos, src_sorted, E);

    const int gatherBlocks = (N + 7) / 8;      // 2 nodes/wave, 4 waves/block
    const int gemmBlocks   = NPAD / 64;

    // --- Layer 1 (fused gather3 + feature expand) ---
    k_l1<<<NPAD / 32, B, 0, stream>>>(Xs, row_start, src_sorted, dinv, W1, b1,
                                      (unsigned int*)Act16, N);
    // --- Layer 2 (MFMA gemm, bf16 in/out) ---
    k_gemm_mfma<<<gemmBlocks, B, 0, stream>>>(Act16, Wt2g, dinv, Hbuf16);
    k_gather<<<gatherBlocks, B, 0, stream>>>(Hbuf16, row_start, src_sorted, dinv, b2, Act16, N);
    // --- Layer 3 (MFMA gemm + gather fused with W4p projection -> P3s) ---
    k_gemm_mfma<<<gemmBlocks, B, 0, stream>>>(Act16, Wt3g, dinv, Hbuf16);
    k_gather_proj<<<gatherBlocks, B, 0, stream>>>(Hbuf16, row_start, src_sorted, dinv, b3, W4p, P3s, N);
    // --- Layer 4 + pool + head (fused, block per graph) ---
    k_tail<<<NGRAPH, B, 0, stream>>>(P3s, row_start, src_sorted, dinv, batch, b4p, out, N);
}

// Round 15
// 162.197 us; speedup vs baseline: 1.0469x; 1.0469x over previous
//
#include <hip/hip_runtime.h>
#include <hip/hip_bf16.h>

#define HID 128
#define NGRAPH 512

typedef __attribute__((ext_vector_type(8))) short short8;   // 8 bf16 (4 VGPR)
typedef __attribute__((ext_vector_type(4))) float f32x4;    // MFMA acc

// bf16 helpers (RNE)
__device__ inline unsigned int f2bf(float f) {
    unsigned int u = __float_as_uint(f);
    return (u + 0x7FFFu + ((u >> 16) & 1u)) >> 16;
}
__device__ inline float bflo(unsigned int w) { return __uint_as_float(w << 16); }
__device__ inline float bfhi(unsigned int w) { return __uint_as_float(w & 0xFFFF0000u); }

// ---------------------------------------------------------------------------
// Setup kernel 1: zero deg + foldW (W4p,b4p) + bf16-transpose W2/W3.
// ---------------------------------------------------------------------------

__device__ inline void wcast_body(const float* __restrict__ W,
                                  unsigned short* __restrict__ Wt) {
    int t = threadIdx.x;   // 1024 threads
#pragma unroll
    for (int i = 0; i < 16; ++i) {
        int flat = i * 1024 + t;
        int n = flat >> 7, k = flat & 127;
        Wt[n * HID + k] = (unsigned short)f2bf(W[k * HID + n]);
    }
}

__global__ void k_setup1(int* __restrict__ deg, int n, int nzb,
                         const float* __restrict__ W4, const float* __restrict__ linW,
                         const float* __restrict__ b4, const float* __restrict__ linb,
                         float* __restrict__ W4p, float* __restrict__ b4p,
                         const float* __restrict__ W2, const float* __restrict__ W3,
                         unsigned short* __restrict__ Wt2, unsigned short* __restrict__ Wt3) {
    if ((int)blockIdx.x == nzb) {
        int idx = threadIdx.x;
        if (idx < 256) {
            int k = idx >> 1, c = idx & 1;
            float a = 0.0f;
            for (int j = 0; j < HID; ++j) a = fmaf(W4[k * HID + j], linW[j * 2 + c], a);
            W4p[idx] = a;
            if (idx < 2) {
                float b = 0.0f;
                for (int j = 0; j < HID; ++j) b = fmaf(b4[j], linW[j * 2 + idx], b);
                b4p[idx] = b + linb[idx];
            }
        }
        return;
    }
    if ((int)blockIdx.x == nzb + 1) { wcast_body(W2, Wt2); return; }
    if ((int)blockIdx.x == nzb + 2) { wcast_body(W3, Wt3); return; }
    int i = blockIdx.x * 1024 + threadIdx.x;
    if (i < n) deg[i] = 0;
}

// degree count; records each edge's position within its dst bucket
__global__ void k_count(const int* __restrict__ ei, int* __restrict__ deg,
                        int* __restrict__ epos, int E) {
    int e = blockIdx.x * blockDim.x + threadIdx.x;
    if (e < E) epos[e] = atomicAdd(&deg[ei[E + e]], 1);
}

// ---------------------------------------------------------------------------
// Fused scan -> row_start; dinv; pre-scaled Xs
// ---------------------------------------------------------------------------
__global__ void k_scan2b(const int* __restrict__ deg, int* __restrict__ row_start,
                         float* __restrict__ dinv, const float* __restrict__ x,
                         float* __restrict__ Xs, int n, int nblocks) {
    __shared__ int rs[16];
    __shared__ int ws[16];
    __shared__ int s_off_sh;
    int lane = threadIdx.x & 63, wid = threadIdx.x >> 6;
    {
        int before = blockIdx.x * 1024;
        int p = 0;
        for (int i = threadIdx.x; i < before; i += 1024) p += deg[i];
#pragma unroll
        for (int off = 32; off; off >>= 1) p += __shfl_down(p, off);
        if (lane == 0) rs[wid] = p;
        __syncthreads();
        if (threadIdx.x == 0) {
            int s = 0;
#pragma unroll
            for (int w = 0; w < 16; ++w) s += rs[w];
            s_off_sh = s;
        }
        __syncthreads();
    }
    int i = blockIdx.x * 1024 + threadIdx.x;
    int v = (i < n) ? deg[i] : 0;
    if (i < n) {
        float dv = rsqrtf((float)v + 1.0f);
        dinv[i] = dv;
        float4 r;
        r.x = x[i * 3 + 0] * dv;
        r.y = x[i * 3 + 1] * dv;
        r.z = x[i * 3 + 2] * dv;
        r.w = 0.0f;
        *(float4*)&Xs[i * 4] = r;
    }
    int xx = v;
#pragma unroll
    for (int off = 1; off < 64; off <<= 1) {
        int t = __shfl_up(xx, off);
        if (lane >= off) xx += t;
    }
    if (lane == 63) ws[wid] = xx;
    __syncthreads();
    int wo = 0;
    for (int w = 0; w < wid; ++w) wo += ws[w];
    int excl = s_off_sh + wo + xx - v;
    if (i < n) row_start[i] = excl;
    if ((int)blockIdx.x == nblocks - 1 && threadIdx.x == 0) {
        int ct = 0;
#pragma unroll
        for (int w = 0; w < 16; ++w) ct += ws[w];
        row_start[n] = s_off_sh + ct;
    }
}

// atomic-free fill using saved positions
__global__ void k_fill(const int* __restrict__ ei, const int* __restrict__ row_start,
                       const int* __restrict__ epos, int* __restrict__ src_sorted, int E) {
    int e = blockIdx.x * blockDim.x + threadIdx.x;
    if (e < E) {
        int s = ei[e];
        int d = ei[E + e];
        src_sorted[row_start[d] + epos[e]] = s;
    }
}

// ---------------------------------------------------------------------------
// Fused layer1 + GEMM2: block = 64 nodes.
//   phase0: stage swizzled W2^T (32 KB LDS)
//   phase1: 3-wide gather (4 lanes/node) -> xs[64][4]
//   phase2: Act tile = bf16(relu(xa.W1+b1)) -> AT LDS (swizzled)
//   phase3: MFMA (A from AT, B from Wt) + dinv scale -> Hout
// ---------------------------------------------------------------------------
__global__ __launch_bounds__(256) void k_l1g2(const float* __restrict__ Xs,
                                              const int* __restrict__ row_start,
                                              const int* __restrict__ src_sorted,
                                              const float* __restrict__ dinv,
                                              const float* __restrict__ W1,
                                              const float* __restrict__ b1,
                                              const unsigned short* __restrict__ Wtg,
                                              unsigned short* __restrict__ Hout, int n) {
    __shared__ unsigned short Wt[HID * HID];   // 32 KB swizzled W2^T
    __shared__ unsigned short AT[64 * HID];    // 16 KB swizzled Act tile / C bounce
    __shared__ float xs[64][4];                // 1 KB

    // phase 0: stage Wt
    {
        int nrow = threadIdx.x >> 1, s = threadIdx.x & 1;
        int xr = (nrow & 7) << 3;
#pragma unroll
        for (int i = 0; i < 8; ++i) {
            int b16 = s * 64 + i * 8;
            *(uint4*)&Wt[nrow * HID + (b16 ^ xr)] = *(const uint4*)&Wtg[nrow * HID + b16];
        }
    }
    // phase 1: 3-wide gather (4 lanes per node)
    {
        int grp = threadIdx.x >> 2, sub = threadIdx.x & 3;
        int v = blockIdx.x * 64 + grp;
        float a0 = 0.f, a1 = 0.f, a2 = 0.f;
        if (v < n) {
            int e0 = row_start[v], e1 = row_start[v + 1];
            for (int e = e0 + sub; e < e1; e += 4) {
                int s2 = src_sorted[e];
                float4 xv = *(const float4*)&Xs[s2 * 4];
                a0 += xv.x; a1 += xv.y; a2 += xv.z;
            }
        }
        a0 += __shfl_xor(a0, 2); a0 += __shfl_xor(a0, 1);
        a1 += __shfl_xor(a1, 2); a1 += __shfl_xor(a1, 1);
        a2 += __shfl_xor(a2, 2); a2 += __shfl_xor(a2, 1);
        if (sub == 0) {
            if (v < n) {
                float dv = dinv[v];
                float4 xv = *(const float4*)&Xs[v * 4];
                xs[grp][0] = (a0 + xv.x) * dv;
                xs[grp][1] = (a1 + xv.y) * dv;
                xs[grp][2] = (a2 + xv.z) * dv;
            } else {
                xs[grp][0] = 0.f; xs[grp][1] = 0.f; xs[grp][2] = 0.f;
            }
        }
    }
    __syncthreads();
    // phase 2: Act tile -> AT (bf16, same XOR swizzle as Wt)
    {
#pragma unroll
        for (int i = 0; i < 16; ++i) {
            int flat = i * 256 + threadIdx.x;     // 64 rows x 64 col-pairs
            int row = flat >> 6, cp = flat & 63;
            float x0 = xs[row][0], x1 = xs[row][1], x2 = xs[row][2];
            int c0 = cp * 2, c1 = c0 + 1;
            float r0 = fmaf(x0, W1[c0], fmaf(x1, W1[HID + c0], fmaf(x2, W1[2 * HID + c0], b1[c0])));
            float r1 = fmaf(x0, W1[c1], fmaf(x1, W1[HID + c1], fmaf(x2, W1[2 * HID + c1], b1[c1])));
            unsigned int w = f2bf(fmaxf(r0, 0.f)) | (f2bf(fmaxf(r1, 0.f)) << 16);
            int soff = (c0 & 7) | ((((c0 >> 3)) ^ (row & 7)) << 3);
            *(unsigned int*)&AT[row * HID + soff] = w;
        }
    }
    __syncthreads();
    // phase 3: MFMA
    int w    = threadIdx.x >> 6;
    int lane = threadIdx.x & 63;
    int g    = lane >> 4;
    int mr   = lane & 15;
    size_t row0 = (size_t)blockIdx.x * 64;
    int arow = w * 16 + mr;
    int axr = (arow & 7) << 3;

    short8 a[4];
#pragma unroll
    for (int ks = 0; ks < 4; ++ks)
        a[ks] = *(const short8*)&AT[arow * HID + ((ks * 32 + g * 8) ^ axr)];

    f32x4 acc[8];
#pragma unroll
    for (int nt = 0; nt < 8; ++nt) acc[nt] = (f32x4){0.f, 0.f, 0.f, 0.f};

#pragma unroll
    for (int nt = 0; nt < 8; ++nt) {
        int nrow = nt * 16 + mr;
        int xr = (nrow & 7) << 3;
        short8 b[4];
#pragma unroll
        for (int ks = 0; ks < 4; ++ks)
            b[ks] = *(const short8*)&Wt[nrow * HID + ((ks * 32 + g * 8) ^ xr)];
#pragma unroll
        for (int ks = 0; ks < 4; ++ks)
            acc[nt] = __builtin_amdgcn_mfma_f32_16x16x32_bf16(a[ks], b[ks], acc[nt], 0, 0, 0);
    }
    __syncthreads();                           // AT reads done; reuse as C tile
    {
        int rrb = w * 16 + g * 4;
#pragma unroll
        for (int j = 0; j < 4; ++j) {
            int rr = rrb + j;
            float dv = dinv[row0 + rr];
#pragma unroll
            for (int nt = 0; nt < 8; ++nt) {
                int col = nt * 16 + mr;
                int idx = rr * HID + ((col & 7) | ((((col >> 3)) ^ (rr & 7)) << 3));
                AT[idx] = (unsigned short)f2bf(acc[nt][j] * dv);
            }
        }
    }
    __syncthreads();
    {
        int rr = threadIdx.x >> 2, s = threadIdx.x & 3;
        int xr = (rr & 7) << 3;
#pragma unroll
        for (int i = 0; i < 4; ++i) {
            int b16 = s * 32 + i * 8;
            uint4 v = *(const uint4*)&AT[rr * HID + (b16 ^ xr)];
            *(uint4*)&Hout[(row0 + rr) * HID + b16] = v;
        }
    }
}

// ---------------------------------------------------------------------------
// MFMA GEMM (layer 3): bf16 X @ Wt -> bf16 H, row-scaled by dinv.
// ---------------------------------------------------------------------------
__global__ __launch_bounds__(256) void k_gemm_mfma(const unsigned short* __restrict__ X,
                                                   const unsigned short* __restrict__ Wtg,
                                                   const float* __restrict__ dinv,
                                                   unsigned short* __restrict__ Hout) {
    __shared__ unsigned short Wt[HID * HID];   // 32 KB
    {
        int nrow = threadIdx.x >> 1, s = threadIdx.x & 1;
        int xr = (nrow & 7) << 3;
#pragma unroll
        for (int i = 0; i < 8; ++i) {
            int b16 = s * 64 + i * 8;
            uint4 src = *(const uint4*)&Wtg[nrow * HID + b16];
            *(uint4*)&Wt[nrow * HID + (b16 ^ xr)] = src;
        }
    }
    __syncthreads();

    int w    = threadIdx.x >> 6;
    int lane = threadIdx.x & 63;
    int g    = lane >> 4;
    int mr   = lane & 15;
    size_t row0 = (size_t)blockIdx.x * 64;
    size_t arow = row0 + w * 16 + mr;

    short8 a[4];
#pragma unroll
    for (int ks = 0; ks < 4; ++ks)
        a[ks] = *(const short8*)&X[arow * HID + ks * 32 + g * 8];

    f32x4 acc[8];
#pragma unroll
    for (int nt = 0; nt < 8; ++nt) acc[nt] = (f32x4){0.f, 0.f, 0.f, 0.f};

#pragma unroll
    for (int nt = 0; nt < 8; ++nt) {
        int nrow = nt * 16 + mr;
        int xr = (nrow & 7) << 3;
        short8 b[4];
#pragma unroll
        for (int ks = 0; ks < 4; ++ks)
            b[ks] = *(const short8*)&Wt[nrow * HID + ((ks * 32 + g * 8) ^ xr)];
#pragma unroll
        for (int ks = 0; ks < 4; ++ks)
            acc[nt] = __builtin_amdgcn_mfma_f32_16x16x32_bf16(a[ks], b[ks], acc[nt], 0, 0, 0);
    }

    __syncthreads();
    {
        int rrb = w * 16 + g * 4;
#pragma unroll
        for (int j = 0; j < 4; ++j) {
            int rr = rrb + j;
            float dv = dinv[row0 + rr];
#pragma unroll
            for (int nt = 0; nt < 8; ++nt) {
                int col = nt * 16 + mr;
                int idx = rr * HID + ((col & 7) | ((((col >> 3)) ^ (rr & 7)) << 3));
                Wt[idx] = (unsigned short)f2bf(acc[nt][j] * dv);
            }
        }
    }
    __syncthreads();
    {
        int rr = threadIdx.x >> 2, s = threadIdx.x & 3;
        int xr = (rr & 7) << 3;
#pragma unroll
        for (int i = 0; i < 4; ++i) {
            int b16 = s * 32 + i * 8;
            uint4 v = *(const uint4*)&Wt[rr * HID + (b16 ^ xr)];
            *(uint4*)&Hout[(row0 + rr) * HID + b16] = v;
        }
    }
}

// ---------------------------------------------------------------------------
// Aggregation: 4 nodes/wave, 16 lanes/row (uint4 = 8 bf16 per lane).
// Exec-masked loads (no duplicate clamped rows); chunk 2 only when deg>16.
// ---------------------------------------------------------------------------
__global__ __launch_bounds__(256) void k_gather(const unsigned short* __restrict__ Hs,
                                                const int* __restrict__ row_start,
                                                const int* __restrict__ src_sorted,
                                                const float* __restrict__ dinv,
                                                const float* __restrict__ bias,
                                                unsigned short* __restrict__ Aout, int n) {
    int wid  = (blockIdx.x * blockDim.x + threadIdx.x) >> 6;
    int lane = threadIdx.x & 63;
    int q = lane >> 4, ql = lane & 15;
    int v0 = wid * 4;
    if (v0 >= n) return;
    int v  = v0 + q;
    bool real = (v < n);
    int vc = real ? v : v0;
    int e0 = row_start[vc], e1 = row_start[vc + 1];
    int deg = e1 - e0;
    int idx0 = (ql < deg) ? src_sorted[e0 + ql] : vc;
    int idx1 = (16 + ql < deg) ? src_sorted[e0 + 16 + ql] : vc;
    float4 accA = make_float4(0.f, 0.f, 0.f, 0.f);
    float4 accB = make_float4(0.f, 0.f, 0.f, 0.f);
    {
        uint4 h[16];
#pragma unroll
        for (int j = 0; j < 16; ++j) {
            int sj = __shfl(idx0, (q << 4) | j);
            uint4 hv = make_uint4(0u, 0u, 0u, 0u);
            if (j < deg) hv = *(const uint4*)&Hs[(size_t)sj * HID + ql * 8];
            h[j] = hv;
        }
#pragma unroll
        for (int j = 0; j < 16; ++j) {
            accA.x += bflo(h[j].x); accA.y += bfhi(h[j].x);
            accA.z += bflo(h[j].y); accA.w += bfhi(h[j].y);
            accB.x += bflo(h[j].z); accB.y += bfhi(h[j].z);
            accB.z += bflo(h[j].w); accB.w += bfhi(h[j].w);
        }
    }
    if (deg > 16) {
        uint4 h[16];
#pragma unroll
        for (int j = 0; j < 16; ++j) {
            int sj = __shfl(idx1, (q << 4) | j);
            uint4 hv = make_uint4(0u, 0u, 0u, 0u);
            if (16 + j < deg) hv = *(const uint4*)&Hs[(size_t)sj * HID + ql * 8];
            h[j] = hv;
        }
#pragma unroll
        for (int j = 0; j < 16; ++j) {
            accA.x += bflo(h[j].x); accA.y += bfhi(h[j].x);
            accA.z += bflo(h[j].y); accA.w += bfhi(h[j].y);
            accB.x += bflo(h[j].z); accB.y += bfhi(h[j].z);
            accB.z += bflo(h[j].w); accB.w += bfhi(h[j].w);
        }
    }
    for (int e = e0 + 32; e < e1; ++e) {       // rare tail deg>32
        int sj = src_sorted[e];
        uint4 h = *(const uint4*)&Hs[(size_t)sj * HID + ql * 8];
        accA.x += bflo(h.x); accA.y += bfhi(h.x);
        accA.z += bflo(h.y); accA.w += bfhi(h.y);
        accB.x += bflo(h.z); accB.y += bfhi(h.z);
        accB.z += bflo(h.w); accB.w += bfhi(h.w);
    }
    float dv = dinv[vc];
    uint4 sv = *(const uint4*)&Hs[(size_t)vc * HID + ql * 8];
    float4 bbA = *(const float4*)&bias[ql * 8 + 0];
    float4 bbB = *(const float4*)&bias[ql * 8 + 4];
    float o0 = fmaxf(fmaf(accA.x + bflo(sv.x), dv, bbA.x), 0.f);
    float o1 = fmaxf(fmaf(accA.y + bfhi(sv.x), dv, bbA.y), 0.f);
    float o2 = fmaxf(fmaf(accA.z + bflo(sv.y), dv, bbA.z), 0.f);
    float o3 = fmaxf(fmaf(accA.w + bfhi(sv.y), dv, bbA.w), 0.f);
    float o4 = fmaxf(fmaf(accB.x + bflo(sv.z), dv, bbB.x), 0.f);
    float o5 = fmaxf(fmaf(accB.y + bfhi(sv.z), dv, bbB.y), 0.f);
    float o6 = fmaxf(fmaf(accB.z + bflo(sv.w), dv, bbB.z), 0.f);
    float o7 = fmaxf(fmaf(accB.w + bfhi(sv.w), dv, bbB.w), 0.f);
    if (real) {
        uint4 o;
        o.x = f2bf(o0) | (f2bf(o1) << 16);
        o.y = f2bf(o2) | (f2bf(o3) << 16);
        o.z = f2bf(o4) | (f2bf(o5) << 16);
        o.w = f2bf(o6) | (f2bf(o7) << 16);
        *(uint4*)&Aout[(size_t)v * HID + ql * 8] = o;
    }
}

// Layer-3 variant: same 4-node gather, then project onto W4p [128,2] -> P3s.
__global__ __launch_bounds__(256) void k_gather_proj(const unsigned short* __restrict__ Hs,
                                                     const int* __restrict__ row_start,
                                                     const int* __restrict__ src_sorted,
                                                     const float* __restrict__ dinv,
                                                     const float* __restrict__ bias,
                                                     const float* __restrict__ W4p,
                                                     float* __restrict__ P3s, int n) {
    int wid  = (blockIdx.x * blockDim.x + threadIdx.x) >> 6;
    int lane = threadIdx.x & 63;
    int q = lane >> 4, ql = lane & 15;
    int v0 = wid * 4;
    if (v0 >= n) return;
    int v  = v0 + q;
    bool real = (v < n);
    int vc = real ? v : v0;
    int e0 = row_start[vc], e1 = row_start[vc + 1];
    int deg = e1 - e0;
    int idx0 = (ql < deg) ? src_sorted[e0 + ql] : vc;
    int idx1 = (16 + ql < deg) ? src_sorted[e0 + 16 + ql] : vc;
    float4 accA = make_float4(0.f, 0.f, 0.f, 0.f);
    float4 accB = make_float4(0.f, 0.f, 0.f, 0.f);
    {
        uint4 h[16];
#pragma unroll
        for (int j = 0; j < 16; ++j) {
            int sj = __shfl(idx0, (q << 4) | j);
            uint4 hv = make_uint4(0u, 0u, 0u, 0u);
            if (j < deg) hv = *(const uint4*)&Hs[(size_t)sj * HID + ql * 8];
            h[j] = hv;
        }
#pragma unroll
        for (int j = 0; j < 16; ++j) {
            accA.x += bflo(h[j].x); accA.y += bfhi(h[j].x);
            accA.z += bflo(h[j].y); accA.w += bfhi(h[j].y);
            accB.x += bflo(h[j].z); accB.y += bfhi(h[j].z);
            accB.z += bflo(h[j].w); accB.w += bfhi(h[j].w);
        }
    }
    if (deg > 16) {
        uint4 h[16];
#pragma unroll
        for (int j = 0; j < 16; ++j) {
            int sj = __shfl(idx1, (q << 4) | j);
            uint4 hv = make_uint4(0u, 0u, 0u, 0u);
            if (16 + j < deg) hv = *(const uint4*)&Hs[(size_t)sj * HID + ql * 8];
            h[j] = hv;
        }
#pragma unroll
        for (int j = 0; j < 16; ++j) {
            accA.x += bflo(h[j].x); accA.y += bfhi(h[j].x);
            accA.z += bflo(h[j].y); accA.w += bfhi(h[j].y);
            accB.x += bflo(h[j].z); accB.y += bfhi(h[j].z);
            accB.z += bflo(h[j].w); accB.w += bfhi(h[j].w);
        }
    }
    for (int e = e0 + 32; e < e1; ++e) {
        int sj = src_sorted[e];
        uint4 h = *(const uint4*)&Hs[(size_t)sj * HID + ql * 8];
        accA.x += bflo(h.x); accA.y += bfhi(h.x);
        accA.z += bflo(h.y); accA.w += bfhi(h.y);
        accB.x += bflo(h.z); accB.y += bfhi(h.z);
        accB.z += bflo(h.w); accB.w += bfhi(h.w);
    }
    float dv = dinv[vc];
    uint4 sv = *(const uint4*)&Hs[(size_t)vc * HID + ql * 8];
    float4 bbA = *(const float4*)&bias[ql * 8 + 0];
    float4 bbB = *(const float4*)&bias[ql * 8 + 4];
    float o0 = fmaxf(fmaf(accA.x + bflo(sv.x), dv, bbA.x), 0.f);
    float o1 = fmaxf(fmaf(accA.y + bfhi(sv.x), dv, bbA.y), 0.f);
    float o2 = fmaxf(fmaf(accA.z + bflo(sv.y), dv, bbA.z), 0.f);
    float o3 = fmaxf(fmaf(accA.w + bfhi(sv.y), dv, bbA.w), 0.f);
    float o4 = fmaxf(fmaf(accB.x + bflo(sv.z), dv, bbB.x), 0.f);
    float o5 = fmaxf(fmaf(accB.y + bfhi(sv.z), dv, bbB.y), 0.f);
    float o6 = fmaxf(fmaf(accB.z + bflo(sv.w), dv, bbB.z), 0.f);
    float o7 = fmaxf(fmaf(accB.w + bfhi(sv.w), dv, bbB.w), 0.f);
    // project lane's 8 cols (k = 8ql..8ql+7) onto W4p[k][2]
    float4 w0 = *(const float4*)&W4p[ql * 16 + 0];
    float4 w1 = *(const float4*)&W4p[ql * 16 + 4];
    float4 w2 = *(const float4*)&W4p[ql * 16 + 8];
    float4 w3 = *(const float4*)&W4p[ql * 16 + 12];
    float p0 = o0 * w0.x + o1 * w0.z + o2 * w1.x + o3 * w1.z
             + o4 * w2.x + o5 * w2.z + o6 * w3.x + o7 * w3.z;
    float p1 = o0 * w0.y + o1 * w0.w + o2 * w1.y + o3 * w1.w
             + o4 * w2.y + o5 * w2.w + o6 * w3.y + o7 * w3.w;
#pragma unroll
    for (int off = 8; off; off >>= 1) {        // xor stays within 16-lane group
        p0 += __shfl_xor(p0, off);
        p1 += __shfl_xor(p1, off);
    }
    if (ql == 0 && real) *(float2*)&P3s[v * 2] = make_float2(p0 * dv, p1 * dv);
}

// ---------------------------------------------------------------------------
// Fused tail: block per graph; layer-4 2-wide gather + mean-pool + head bias.
// ---------------------------------------------------------------------------
__global__ __launch_bounds__(256) void k_tail(const float* __restrict__ P3s,
                                              const int* __restrict__ row_start,
                                              const int* __restrict__ src_sorted,
                                              const float* __restrict__ dinv,
                                              const int* __restrict__ batch,
                                              const float* __restrict__ b4p,
                                              float* __restrict__ out, int n) {
    int g = blockIdx.x;
    int lo = 0, hi = n;
    while (lo < hi) { int m = (lo + hi) >> 1; if (batch[m] < g) lo = m + 1; else hi = m; }
    int start = lo;
    hi = n;
    while (lo < hi) { int m = (lo + hi) >> 1; if (batch[m] < g + 1) lo = m + 1; else hi = m; }
    int end = lo;

    int grp = threadIdx.x >> 3, sub = threadIdx.x & 7;
    float gx = 0.f, gy = 0.f;
    for (int v = start + grp; v < end; v += 32) {
        float ax = 0.f, ay = 0.f;
        int e0 = row_start[v], e1 = row_start[v + 1];
        for (int e = e0 + sub; e < e1; e += 8) {
            int s = src_sorted[e];
            float2 ps = *(const float2*)&P3s[s * 2];
            ax += ps.x;
            ay += ps.y;
        }
#pragma unroll
        for (int off = 4; off; off >>= 1) {
            ax += __shfl_down(ax, off);
            ay += __shfl_down(ay, off);
        }
        if (sub == 0) {
            float dv = dinv[v];
            float2 pv = *(const float2*)&P3s[v * 2];
            gx += (ax + pv.x) * dv;
            gy += (ay + pv.y) * dv;
        }
    }
    __shared__ float red[64];
    if (sub == 0) { red[grp] = gx; red[grp + 32] = gy; }
    __syncthreads();
    if (threadIdx.x < 64) {
        float sx = (threadIdx.x < 32) ? red[threadIdx.x] : 0.f;
        float sy = (threadIdx.x < 32) ? red[threadIdx.x + 32] : 0.f;
#pragma unroll
        for (int off = 16; off; off >>= 1) {
            sx += __shfl_down(sx, off);
            sy += __shfl_down(sy, off);
        }
        if (threadIdx.x == 0) {
            float inv = 1.0f / fmaxf((float)(end - start), 1.0f);
            out[g * 2 + 0] = sx * inv + b4p[0];
            out[g * 2 + 1] = sy * inv + b4p[1];
        }
    }
}

// ---------------------------------------------------------------------------

extern "C" void kernel_launch(void* const* d_in, const int* in_sizes, int n_in,
                              void* d_out, int out_size, void* d_ws, size_t ws_size,
                              hipStream_t stream) {
    const float* x    = (const float*)d_in[0];
    const float* W1   = (const float*)d_in[1];
    const float* b1   = (const float*)d_in[2];
    const float* W2   = (const float*)d_in[3];
    const float* b2   = (const float*)d_in[4];
    const float* W3   = (const float*)d_in[5];
    const float* b3   = (const float*)d_in[6];
    const float* W4   = (const float*)d_in[7];
    const float* b4   = (const float*)d_in[8];
    const float* linW = (const float*)d_in[9];
    const float* linb = (const float*)d_in[10];
    const int*   ei   = (const int*)d_in[11];   // [2,E]
    const int*   batch= (const int*)d_in[12];   // [N]
    float* out        = (float*)d_out;

    const int N = in_sizes[0] / 3;
    const int E = in_sizes[11] / 2;
    const int NPAD = ((N + 127) / 128) * 128;   // 64 | NPAD
    const int NB1024 = (N + 1023) / 1024;

    // Workspace layout (4-B slots)
    float* ws = (float*)d_ws;
    float* dinv       = ws;                             // 50176
    int*   deg_i      = (int*)(ws + 50176);             // 50176
    int*   row_start  = (int*)(ws + 100352);            // 50432 (N+1)
    int*   epos       = (int*)(ws + 150784);            // 600064
    float* W4p        = ws + 750912;                    // 256
    float* b4p        = ws + 751168;                    // 64 (2 used)
    int*   src_sorted = (int*)(ws + 751232);            // 600064
    float* P3s        = ws + 1351296;                   // N*2 (pad 100352)
    float* Xs         = ws + 1451648;                   // N*4 (own region now)
    unsigned short* Hbuf16 = (unsigned short*)(ws + 1652352);         // NPAD*128 bf16
    unsigned short* Act16  = (unsigned short*)(ws + 1652352 + (size_t)NPAD * 64);
    unsigned short* Wt2g   = (unsigned short*)(ws + 1652352 + 2 * (size_t)NPAD * 64);
    unsigned short* Wt3g   = Wt2g + HID * HID;          // 16384 bf16 each

    const int B = 256;

    // --- Setup ---
    k_setup1<<<NB1024 + 3, 1024, 0, stream>>>(deg_i, N, NB1024, W4, linW, b4, linb,
                                              W4p, b4p, W2, W3, Wt2g, Wt3g);
    k_count<<<(E + B - 1) / B, B, 0, stream>>>(ei, deg_i, epos, E);
    k_scan2b<<<NB1024, 1024, 0, stream>>>(deg_i, row_start, dinv, x, Xs, N, NB1024);
    k_fill<<<(E + B - 1) / B, B, 0, stream>>>(ei, row_start, epos, src_sorted, E);

    const int gatherBlocks = (N + 15) / 16;    // 4 nodes/wave, 4 waves/block
    const int gemmBlocks   = NPAD / 64;

    // --- Layer 1 + GEMM2 fused ---
    k_l1g2<<<gemmBlocks, B, 0, stream>>>(Xs, row_start, src_sorted, dinv, W1, b1,
                                         Wt2g, Hbuf16, N);
    // --- Layer 2 aggregation ---
    k_gather<<<gatherBlocks, B, 0, stream>>>(Hbuf16, row_start, src_sorted, dinv, b2, Act16, N);
    // --- Layer 3 GEMM + aggregation w/ projection ---
    k_gemm_mfma<<<gemmBlocks, B, 0, stream>>>(Act16, Wt3g, dinv, Hbuf16);
    k_gather_proj<<<gatherBlocks, B, 0, stream>>>(Hbuf16, row_start, src_sorted, dinv, b3, W4p, P3s, N);
    // --- Layer 4 + pool + head ---
    k_tail<<<NGRAPH, B, 0, stream>>>(P3s, row_start, src_sorted, dinv, batch, b4p, out, N);
}

// Round 16
// 157.127 us; speedup vs baseline: 1.0807x; 1.0323x over previous
//
#include <hip/hip_runtime.h>
#include <hip/hip_bf16.h>

#define HID 128
#define NGRAPH 512

typedef __attribute__((ext_vector_type(8))) short short8;   // 8 bf16 (4 VGPR)
typedef __attribute__((ext_vector_type(4))) float f32x4;    // MFMA acc

// bf16 helpers (RNE)
__device__ inline unsigned int f2bf(float f) {
    unsigned int u = __float_as_uint(f);
    return (u + 0x7FFFu + ((u >> 16) & 1u)) >> 16;
}
__device__ inline float bflo(unsigned int w) { return __uint_as_float(w << 16); }
__device__ inline float bfhi(unsigned int w) { return __uint_as_float(w & 0xFFFF0000u); }

// ---------------------------------------------------------------------------
// Setup kernel 1: zero deg + foldW (W4p,b4p) + bf16-transpose W2/W3.
// ---------------------------------------------------------------------------

__device__ inline void wcast_body(const float* __restrict__ W,
                                  unsigned short* __restrict__ Wt) {
    int t = threadIdx.x;   // 1024 threads
#pragma unroll
    for (int i = 0; i < 16; ++i) {
        int flat = i * 1024 + t;
        int n = flat >> 7, k = flat & 127;
        Wt[n * HID + k] = (unsigned short)f2bf(W[k * HID + n]);
    }
}

__global__ void k_setup1(int* __restrict__ deg, int n, int nzb,
                         const float* __restrict__ W4, const float* __restrict__ linW,
                         const float* __restrict__ b4, const float* __restrict__ linb,
                         float* __restrict__ W4p, float* __restrict__ b4p,
                         const float* __restrict__ W2, const float* __restrict__ W3,
                         unsigned short* __restrict__ Wt2, unsigned short* __restrict__ Wt3) {
    if ((int)blockIdx.x == nzb) {
        int idx = threadIdx.x;
        if (idx < 256) {
            int k = idx >> 1, c = idx & 1;
            float a = 0.0f;
            for (int j = 0; j < HID; ++j) a = fmaf(W4[k * HID + j], linW[j * 2 + c], a);
            W4p[idx] = a;
            if (idx < 2) {
                float b = 0.0f;
                for (int j = 0; j < HID; ++j) b = fmaf(b4[j], linW[j * 2 + idx], b);
                b4p[idx] = b + linb[idx];
            }
        }
        return;
    }
    if ((int)blockIdx.x == nzb + 1) { wcast_body(W2, Wt2); return; }
    if ((int)blockIdx.x == nzb + 2) { wcast_body(W3, Wt3); return; }
    int i = blockIdx.x * 1024 + threadIdx.x;
    if (i < n) deg[i] = 0;
}

// degree count; records each edge's position within its dst bucket
__global__ void k_count(const int* __restrict__ ei, int* __restrict__ deg,
                        int* __restrict__ epos, int E) {
    int e = blockIdx.x * blockDim.x + threadIdx.x;
    if (e < E) epos[e] = atomicAdd(&deg[ei[E + e]], 1);
}

// ---------------------------------------------------------------------------
// Fused scan -> row_start; dinv; pre-scaled Xs
// ---------------------------------------------------------------------------
__global__ void k_scan2b(const int* __restrict__ deg, int* __restrict__ row_start,
                         float* __restrict__ dinv, const float* __restrict__ x,
                         float* __restrict__ Xs, int n, int nblocks) {
    __shared__ int rs[16];
    __shared__ int ws[16];
    __shared__ int s_off_sh;
    int lane = threadIdx.x & 63, wid = threadIdx.x >> 6;
    {
        int before = blockIdx.x * 1024;
        int p = 0;
        for (int i = threadIdx.x; i < before; i += 1024) p += deg[i];
#pragma unroll
        for (int off = 32; off; off >>= 1) p += __shfl_down(p, off);
        if (lane == 0) rs[wid] = p;
        __syncthreads();
        if (threadIdx.x == 0) {
            int s = 0;
#pragma unroll
            for (int w = 0; w < 16; ++w) s += rs[w];
            s_off_sh = s;
        }
        __syncthreads();
    }
    int i = blockIdx.x * 1024 + threadIdx.x;
    int v = (i < n) ? deg[i] : 0;
    if (i < n) {
        float dv = rsqrtf((float)v + 1.0f);
        dinv[i] = dv;
        float4 r;
        r.x = x[i * 3 + 0] * dv;
        r.y = x[i * 3 + 1] * dv;
        r.z = x[i * 3 + 2] * dv;
        r.w = 0.0f;
        *(float4*)&Xs[i * 4] = r;
    }
    int xx = v;
#pragma unroll
    for (int off = 1; off < 64; off <<= 1) {
        int t = __shfl_up(xx, off);
        if (lane >= off) xx += t;
    }
    if (lane == 63) ws[wid] = xx;
    __syncthreads();
    int wo = 0;
    for (int w = 0; w < wid; ++w) wo += ws[w];
    int excl = s_off_sh + wo + xx - v;
    if (i < n) row_start[i] = excl;
    if ((int)blockIdx.x == nblocks - 1 && threadIdx.x == 0) {
        int ct = 0;
#pragma unroll
        for (int w = 0; w < 16; ++w) ct += ws[w];
        row_start[n] = s_off_sh + ct;
    }
}

// atomic-free fill using saved positions
__global__ void k_fill(const int* __restrict__ ei, const int* __restrict__ row_start,
                       const int* __restrict__ epos, int* __restrict__ src_sorted, int E) {
    int e = blockIdx.x * blockDim.x + threadIdx.x;
    if (e < E) {
        int s = ei[e];
        int d = ei[E + e];
        src_sorted[row_start[d] + epos[e]] = s;
    }
}

// ---------------------------------------------------------------------------
// Fused layer1 + GEMM2 (as R15): gather3 -> Act tile in LDS -> MFMA -> Hout
// ---------------------------------------------------------------------------
__global__ __launch_bounds__(256) void k_l1g2(const float* __restrict__ Xs,
                                              const int* __restrict__ row_start,
                                              const int* __restrict__ src_sorted,
                                              const float* __restrict__ dinv,
                                              const float* __restrict__ W1,
                                              const float* __restrict__ b1,
                                              const unsigned short* __restrict__ Wtg,
                                              unsigned short* __restrict__ Hout, int n) {
    __shared__ unsigned short Wt[HID * HID];   // 32 KB swizzled W2^T
    __shared__ unsigned short AT[64 * HID];    // 16 KB swizzled Act tile / C bounce
    __shared__ float xs[64][4];                // 1 KB

    {
        int nrow = threadIdx.x >> 1, s = threadIdx.x & 1;
        int xr = (nrow & 7) << 3;
#pragma unroll
        for (int i = 0; i < 8; ++i) {
            int b16 = s * 64 + i * 8;
            *(uint4*)&Wt[nrow * HID + (b16 ^ xr)] = *(const uint4*)&Wtg[nrow * HID + b16];
        }
    }
    {
        int grp = threadIdx.x >> 2, sub = threadIdx.x & 3;
        int v = blockIdx.x * 64 + grp;
        float a0 = 0.f, a1 = 0.f, a2 = 0.f;
        if (v < n) {
            int e0 = row_start[v], e1 = row_start[v + 1];
            for (int e = e0 + sub; e < e1; e += 4) {
                int s2 = src_sorted[e];
                float4 xv = *(const float4*)&Xs[s2 * 4];
                a0 += xv.x; a1 += xv.y; a2 += xv.z;
            }
        }
        a0 += __shfl_xor(a0, 2); a0 += __shfl_xor(a0, 1);
        a1 += __shfl_xor(a1, 2); a1 += __shfl_xor(a1, 1);
        a2 += __shfl_xor(a2, 2); a2 += __shfl_xor(a2, 1);
        if (sub == 0) {
            if (v < n) {
                float dv = dinv[v];
                float4 xv = *(const float4*)&Xs[v * 4];
                xs[grp][0] = (a0 + xv.x) * dv;
                xs[grp][1] = (a1 + xv.y) * dv;
                xs[grp][2] = (a2 + xv.z) * dv;
            } else {
                xs[grp][0] = 0.f; xs[grp][1] = 0.f; xs[grp][2] = 0.f;
            }
        }
    }
    __syncthreads();
    {
#pragma unroll
        for (int i = 0; i < 16; ++i) {
            int flat = i * 256 + threadIdx.x;
            int row = flat >> 6, cp = flat & 63;
            float x0 = xs[row][0], x1 = xs[row][1], x2 = xs[row][2];
            int c0 = cp * 2, c1 = c0 + 1;
            float r0 = fmaf(x0, W1[c0], fmaf(x1, W1[HID + c0], fmaf(x2, W1[2 * HID + c0], b1[c0])));
            float r1 = fmaf(x0, W1[c1], fmaf(x1, W1[HID + c1], fmaf(x2, W1[2 * HID + c1], b1[c1])));
            unsigned int w = f2bf(fmaxf(r0, 0.f)) | (f2bf(fmaxf(r1, 0.f)) << 16);
            int soff = (c0 & 7) | ((((c0 >> 3)) ^ (row & 7)) << 3);
            *(unsigned int*)&AT[row * HID + soff] = w;
        }
    }
    __syncthreads();
    int w    = threadIdx.x >> 6;
    int lane = threadIdx.x & 63;
    int g    = lane >> 4;
    int mr   = lane & 15;
    size_t row0 = (size_t)blockIdx.x * 64;
    int arow = w * 16 + mr;
    int axr = (arow & 7) << 3;

    short8 a[4];
#pragma unroll
    for (int ks = 0; ks < 4; ++ks)
        a[ks] = *(const short8*)&AT[arow * HID + ((ks * 32 + g * 8) ^ axr)];

    f32x4 acc[8];
#pragma unroll
    for (int nt = 0; nt < 8; ++nt) acc[nt] = (f32x4){0.f, 0.f, 0.f, 0.f};

#pragma unroll
    for (int nt = 0; nt < 8; ++nt) {
        int nrow = nt * 16 + mr;
        int xr = (nrow & 7) << 3;
        short8 b[4];
#pragma unroll
        for (int ks = 0; ks < 4; ++ks)
            b[ks] = *(const short8*)&Wt[nrow * HID + ((ks * 32 + g * 8) ^ xr)];
#pragma unroll
        for (int ks = 0; ks < 4; ++ks)
            acc[nt] = __builtin_amdgcn_mfma_f32_16x16x32_bf16(a[ks], b[ks], acc[nt], 0, 0, 0);
    }
    __syncthreads();
    {
        int rrb = w * 16 + g * 4;
#pragma unroll
        for (int j = 0; j < 4; ++j) {
            int rr = rrb + j;
            float dv = dinv[row0 + rr];
#pragma unroll
            for (int nt = 0; nt < 8; ++nt) {
                int col = nt * 16 + mr;
                int idx = rr * HID + ((col & 7) | ((((col >> 3)) ^ (rr & 7)) << 3));
                AT[idx] = (unsigned short)f2bf(acc[nt][j] * dv);
            }
        }
    }
    __syncthreads();
    {
        int rr = threadIdx.x >> 2, s = threadIdx.x & 3;
        int xr = (rr & 7) << 3;
#pragma unroll
        for (int i = 0; i < 4; ++i) {
            int b16 = s * 32 + i * 8;
            uint4 v = *(const uint4*)&AT[rr * HID + (b16 ^ xr)];
            *(uint4*)&Hout[(row0 + rr) * HID + b16] = v;
        }
    }
}

// ---------------------------------------------------------------------------
// Fused layer-2 gather + layer-3 GEMM: block = 64 nodes.
//   phase0: stage swizzled W3^T
//   phase1: 4 passes x (4 nodes/wave gather from Hs) -> bf16 AT tile (swizzled)
//   phase2: MFMA + dinv scale -> Hout (different buffer than Hs!)
// ---------------------------------------------------------------------------
__global__ __launch_bounds__(256) void k_gagm(const unsigned short* __restrict__ Hs,
                                              const int* __restrict__ row_start,
                                              const int* __restrict__ src_sorted,
                                              const float* __restrict__ dinv,
                                              const float* __restrict__ bias,
                                              const unsigned short* __restrict__ Wtg,
                                              unsigned short* __restrict__ Hout, int n) {
    __shared__ unsigned short Wt[HID * HID];   // 32 KB swizzled W3^T
    __shared__ unsigned short AT[64 * HID];    // 16 KB swizzled A tile / C bounce

    {
        int nrow = threadIdx.x >> 1, s = threadIdx.x & 1;
        int xr = (nrow & 7) << 3;
#pragma unroll
        for (int i = 0; i < 8; ++i) {
            int b16 = s * 64 + i * 8;
            *(uint4*)&Wt[nrow * HID + (b16 ^ xr)] = *(const uint4*)&Wtg[nrow * HID + b16];
        }
    }

    int w    = threadIdx.x >> 6;
    int lane = threadIdx.x & 63;
    int q = lane >> 4, ql = lane & 15;
    size_t row0 = (size_t)blockIdx.x * 64;

    // phase 1: gather 64 rows (4 passes of 16)
    for (int pass = 0; pass < 4; ++pass) {
        int r = pass * 16 + w * 4 + q;           // row within tile, 0..63
        int v = (int)row0 + r;
        int vc = (v < n) ? v : (n - 1);
        int e0 = row_start[vc], e1 = row_start[vc + 1];
        int deg = e1 - e0;
        int idx0 = (ql < deg) ? src_sorted[e0 + ql] : vc;
        int idx1 = (16 + ql < deg) ? src_sorted[e0 + 16 + ql] : vc;
        float4 accA = make_float4(0.f, 0.f, 0.f, 0.f);
        float4 accB = make_float4(0.f, 0.f, 0.f, 0.f);
        {
            uint4 h[16];
#pragma unroll
            for (int j = 0; j < 16; ++j) {
                int sj = __shfl(idx0, (q << 4) | j);
                uint4 hv = make_uint4(0u, 0u, 0u, 0u);
                if (j < deg) hv = *(const uint4*)&Hs[(size_t)sj * HID + ql * 8];
                h[j] = hv;
            }
#pragma unroll
            for (int j = 0; j < 16; ++j) {
                accA.x += bflo(h[j].x); accA.y += bfhi(h[j].x);
                accA.z += bflo(h[j].y); accA.w += bfhi(h[j].y);
                accB.x += bflo(h[j].z); accB.y += bfhi(h[j].z);
                accB.z += bflo(h[j].w); accB.w += bfhi(h[j].w);
            }
        }
        if (deg > 16) {
            uint4 h[16];
#pragma unroll
            for (int j = 0; j < 16; ++j) {
                int sj = __shfl(idx1, (q << 4) | j);
                uint4 hv = make_uint4(0u, 0u, 0u, 0u);
                if (16 + j < deg) hv = *(const uint4*)&Hs[(size_t)sj * HID + ql * 8];
                h[j] = hv;
            }
#pragma unroll
            for (int j = 0; j < 16; ++j) {
                accA.x += bflo(h[j].x); accA.y += bfhi(h[j].x);
                accA.z += bflo(h[j].y); accA.w += bfhi(h[j].y);
                accB.x += bflo(h[j].z); accB.y += bfhi(h[j].z);
                accB.z += bflo(h[j].w); accB.w += bfhi(h[j].w);
            }
        }
        for (int e = e0 + 32; e < e1; ++e) {     // rare deg>32 tail
            int sj = src_sorted[e];
            uint4 h = *(const uint4*)&Hs[(size_t)sj * HID + ql * 8];
            accA.x += bflo(h.x); accA.y += bfhi(h.x);
            accA.z += bflo(h.y); accA.w += bfhi(h.y);
            accB.x += bflo(h.z); accB.y += bfhi(h.z);
            accB.z += bflo(h.w); accB.w += bfhi(h.w);
        }
        float dv = dinv[vc];
        uint4 sv = *(const uint4*)&Hs[(size_t)vc * HID + ql * 8];
        float4 bbA = *(const float4*)&bias[ql * 8 + 0];
        float4 bbB = *(const float4*)&bias[ql * 8 + 4];
        float o0 = fmaxf(fmaf(accA.x + bflo(sv.x), dv, bbA.x), 0.f);
        float o1 = fmaxf(fmaf(accA.y + bfhi(sv.x), dv, bbA.y), 0.f);
        float o2 = fmaxf(fmaf(accA.z + bflo(sv.y), dv, bbA.z), 0.f);
        float o3 = fmaxf(fmaf(accA.w + bfhi(sv.y), dv, bbA.w), 0.f);
        float o4 = fmaxf(fmaf(accB.x + bflo(sv.z), dv, bbB.x), 0.f);
        float o5 = fmaxf(fmaf(accB.y + bfhi(sv.z), dv, bbB.y), 0.f);
        float o6 = fmaxf(fmaf(accB.z + bflo(sv.w), dv, bbB.z), 0.f);
        float o7 = fmaxf(fmaf(accB.w + bfhi(sv.w), dv, bbB.w), 0.f);
        uint4 o;
        o.x = f2bf(o0) | (f2bf(o1) << 16);
        o.y = f2bf(o2) | (f2bf(o3) << 16);
        o.z = f2bf(o4) | (f2bf(o5) << 16);
        o.w = f2bf(o6) | (f2bf(o7) << 16);
        int chunk = ql ^ (r & 7);                // XOR swizzle (8-bf16 chunk units)
        *(uint4*)&AT[r * HID + chunk * 8] = o;
    }
    __syncthreads();

    // phase 2: MFMA (A from AT, B from Wt)
    int g  = lane >> 4;
    int mr = lane & 15;
    int arow = w * 16 + mr;
    int axr = (arow & 7) << 3;

    short8 a[4];
#pragma unroll
    for (int ks = 0; ks < 4; ++ks)
        a[ks] = *(const short8*)&AT[arow * HID + ((ks * 32 + g * 8) ^ axr)];

    f32x4 acc[8];
#pragma unroll
    for (int nt = 0; nt < 8; ++nt) acc[nt] = (f32x4){0.f, 0.f, 0.f, 0.f};

#pragma unroll
    for (int nt = 0; nt < 8; ++nt) {
        int nrow = nt * 16 + mr;
        int xr = (nrow & 7) << 3;
        short8 b[4];
#pragma unroll
        for (int ks = 0; ks < 4; ++ks)
            b[ks] = *(const short8*)&Wt[nrow * HID + ((ks * 32 + g * 8) ^ xr)];
#pragma unroll
        for (int ks = 0; ks < 4; ++ks)
            acc[nt] = __builtin_amdgcn_mfma_f32_16x16x32_bf16(a[ks], b[ks], acc[nt], 0, 0, 0);
    }
    __syncthreads();
    {
        int rrb = w * 16 + g * 4;
#pragma unroll
        for (int j = 0; j < 4; ++j) {
            int rr = rrb + j;
            float dv = dinv[row0 + rr];
#pragma unroll
            for (int nt = 0; nt < 8; ++nt) {
                int col = nt * 16 + mr;
                int idx = rr * HID + ((col & 7) | ((((col >> 3)) ^ (rr & 7)) << 3));
                AT[idx] = (unsigned short)f2bf(acc[nt][j] * dv);
            }
        }
    }
    __syncthreads();
    {
        int rr = threadIdx.x >> 2, s = threadIdx.x & 3;
        int xr = (rr & 7) << 3;
#pragma unroll
        for (int i = 0; i < 4; ++i) {
            int b16 = s * 32 + i * 8;
            uint4 v = *(const uint4*)&AT[rr * HID + (b16 ^ xr)];
            *(uint4*)&Hout[(row0 + rr) * HID + b16] = v;
        }
    }
}

// ---------------------------------------------------------------------------
// Layer-3 aggregation + W4p projection -> P3s (4 nodes/wave, uint4 lanes)
// ---------------------------------------------------------------------------
__global__ __launch_bounds__(256) void k_gather_proj(const unsigned short* __restrict__ Hs,
                                                     const int* __restrict__ row_start,
                                                     const int* __restrict__ src_sorted,
                                                     const float* __restrict__ dinv,
                                                     const float* __restrict__ bias,
                                                     const float* __restrict__ W4p,
                                                     float* __restrict__ P3s, int n) {
    int wid  = (blockIdx.x * blockDim.x + threadIdx.x) >> 6;
    int lane = threadIdx.x & 63;
    int q = lane >> 4, ql = lane & 15;
    int v0 = wid * 4;
    if (v0 >= n) return;
    int v  = v0 + q;
    bool real = (v < n);
    int vc = real ? v : v0;
    int e0 = row_start[vc], e1 = row_start[vc + 1];
    int deg = e1 - e0;
    int idx0 = (ql < deg) ? src_sorted[e0 + ql] : vc;
    int idx1 = (16 + ql < deg) ? src_sorted[e0 + 16 + ql] : vc;
    float4 accA = make_float4(0.f, 0.f, 0.f, 0.f);
    float4 accB = make_float4(0.f, 0.f, 0.f, 0.f);
    {
        uint4 h[16];
#pragma unroll
        for (int j = 0; j < 16; ++j) {
            int sj = __shfl(idx0, (q << 4) | j);
            uint4 hv = make_uint4(0u, 0u, 0u, 0u);
            if (j < deg) hv = *(const uint4*)&Hs[(size_t)sj * HID + ql * 8];
            h[j] = hv;
        }
#pragma unroll
        for (int j = 0; j < 16; ++j) {
            accA.x += bflo(h[j].x); accA.y += bfhi(h[j].x);
            accA.z += bflo(h[j].y); accA.w += bfhi(h[j].y);
            accB.x += bflo(h[j].z); accB.y += bfhi(h[j].z);
            accB.z += bflo(h[j].w); accB.w += bfhi(h[j].w);
        }
    }
    if (deg > 16) {
        uint4 h[16];
#pragma unroll
        for (int j = 0; j < 16; ++j) {
            int sj = __shfl(idx1, (q << 4) | j);
            uint4 hv = make_uint4(0u, 0u, 0u, 0u);
            if (16 + j < deg) hv = *(const uint4*)&Hs[(size_t)sj * HID + ql * 8];
            h[j] = hv;
        }
#pragma unroll
        for (int j = 0; j < 16; ++j) {
            accA.x += bflo(h[j].x); accA.y += bfhi(h[j].x);
            accA.z += bflo(h[j].y); accA.w += bfhi(h[j].y);
            accB.x += bflo(h[j].z); accB.y += bfhi(h[j].z);
            accB.z += bflo(h[j].w); accB.w += bfhi(h[j].w);
        }
    }
    for (int e = e0 + 32; e < e1; ++e) {
        int sj = src_sorted[e];
        uint4 h = *(const uint4*)&Hs[(size_t)sj * HID + ql * 8];
        accA.x += bflo(h.x); accA.y += bfhi(h.x);
        accA.z += bflo(h.y); accA.w += bfhi(h.y);
        accB.x += bflo(h.z); accB.y += bfhi(h.z);
        accB.z += bflo(h.w); accB.w += bfhi(h.w);
    }
    float dv = dinv[vc];
    uint4 sv = *(const uint4*)&Hs[(size_t)vc * HID + ql * 8];
    float4 bbA = *(const float4*)&bias[ql * 8 + 0];
    float4 bbB = *(const float4*)&bias[ql * 8 + 4];
    float o0 = fmaxf(fmaf(accA.x + bflo(sv.x), dv, bbA.x), 0.f);
    float o1 = fmaxf(fmaf(accA.y + bfhi(sv.x), dv, bbA.y), 0.f);
    float o2 = fmaxf(fmaf(accA.z + bflo(sv.y), dv, bbA.z), 0.f);
    float o3 = fmaxf(fmaf(accA.w + bfhi(sv.y), dv, bbA.w), 0.f);
    float o4 = fmaxf(fmaf(accB.x + bflo(sv.z), dv, bbB.x), 0.f);
    float o5 = fmaxf(fmaf(accB.y + bfhi(sv.z), dv, bbB.y), 0.f);
    float o6 = fmaxf(fmaf(accB.z + bflo(sv.w), dv, bbB.z), 0.f);
    float o7 = fmaxf(fmaf(accB.w + bfhi(sv.w), dv, bbB.w), 0.f);
    float4 w0 = *(const float4*)&W4p[ql * 16 + 0];
    float4 w1 = *(const float4*)&W4p[ql * 16 + 4];
    float4 w2 = *(const float4*)&W4p[ql * 16 + 8];
    float4 w3 = *(const float4*)&W4p[ql * 16 + 12];
    float p0 = o0 * w0.x + o1 * w0.z + o2 * w1.x + o3 * w1.z
             + o4 * w2.x + o5 * w2.z + o6 * w3.x + o7 * w3.z;
    float p1 = o0 * w0.y + o1 * w0.w + o2 * w1.y + o3 * w1.w
             + o4 * w2.y + o5 * w2.w + o6 * w3.y + o7 * w3.w;
#pragma unroll
    for (int off = 8; off; off >>= 1) {
        p0 += __shfl_xor(p0, off);
        p1 += __shfl_xor(p1, off);
    }
    if (ql == 0 && real) *(float2*)&P3s[v * 2] = make_float2(p0 * dv, p1 * dv);
}

// ---------------------------------------------------------------------------
// Fused tail: block per graph; layer-4 2-wide gather + mean-pool + head bias.
// ---------------------------------------------------------------------------
__global__ __launch_bounds__(256) void k_tail(const float* __restrict__ P3s,
                                              const int* __restrict__ row_start,
                                              const int* __restrict__ src_sorted,
                                              const float* __restrict__ dinv,
                                              const int* __restrict__ batch,
                                              const float* __restrict__ b4p,
                                              float* __restrict__ out, int n) {
    int g = blockIdx.x;
    int lo = 0, hi = n;
    while (lo < hi) { int m = (lo + hi) >> 1; if (batch[m] < g) lo = m + 1; else hi = m; }
    int start = lo;
    hi = n;
    while (lo < hi) { int m = (lo + hi) >> 1; if (batch[m] < g + 1) lo = m + 1; else hi = m; }
    int end = lo;

    int grp = threadIdx.x >> 3, sub = threadIdx.x & 7;
    float gx = 0.f, gy = 0.f;
    for (int v = start + grp; v < end; v += 32) {
        float ax = 0.f, ay = 0.f;
        int e0 = row_start[v], e1 = row_start[v + 1];
        for (int e = e0 + sub; e < e1; e += 8) {
            int s = src_sorted[e];
            float2 ps = *(const float2*)&P3s[s * 2];
            ax += ps.x;
            ay += ps.y;
        }
#pragma unroll
        for (int off = 4; off; off >>= 1) {
            ax += __shfl_down(ax, off);
            ay += __shfl_down(ay, off);
        }
        if (sub == 0) {
            float dv = dinv[v];
            float2 pv = *(const float2*)&P3s[v * 2];
            gx += (ax + pv.x) * dv;
            gy += (ay + pv.y) * dv;
        }
    }
    __shared__ float red[64];
    if (sub == 0) { red[grp] = gx; red[grp + 32] = gy; }
    __syncthreads();
    if (threadIdx.x < 64) {
        float sx = (threadIdx.x < 32) ? red[threadIdx.x] : 0.f;
        float sy = (threadIdx.x < 32) ? red[threadIdx.x + 32] : 0.f;
#pragma unroll
        for (int off = 16; off; off >>= 1) {
            sx += __shfl_down(sx, off);
            sy += __shfl_down(sy, off);
        }
        if (threadIdx.x == 0) {
            float inv = 1.0f / fmaxf((float)(end - start), 1.0f);
            out[g * 2 + 0] = sx * inv + b4p[0];
            out[g * 2 + 1] = sy * inv + b4p[1];
        }
    }
}

// ---------------------------------------------------------------------------

extern "C" void kernel_launch(void* const* d_in, const int* in_sizes, int n_in,
                              void* d_out, int out_size, void* d_ws, size_t ws_size,
                              hipStream_t stream) {
    const float* x    = (const float*)d_in[0];
    const float* W1   = (const float*)d_in[1];
    const float* b1   = (const float*)d_in[2];
    const float* W2   = (const float*)d_in[3];
    const float* b2   = (const float*)d_in[4];
    const float* W3   = (const float*)d_in[5];
    const float* b3   = (const float*)d_in[6];
    const float* W4   = (const float*)d_in[7];
    const float* b4   = (const float*)d_in[8];
    const float* linW = (const float*)d_in[9];
    const float* linb = (const float*)d_in[10];
    const int*   ei   = (const int*)d_in[11];   // [2,E]
    const int*   batch= (const int*)d_in[12];   // [N]
    float* out        = (float*)d_out;

    const int N = in_sizes[0] / 3;
    const int E = in_sizes[11] / 2;
    const int NPAD = ((N + 127) / 128) * 128;   // 64 | NPAD
    const int NB1024 = (N + 1023) / 1024;

    // Workspace layout (4-B slots)
    float* ws = (float*)d_ws;
    float* dinv       = ws;                             // 50176
    int*   deg_i      = (int*)(ws + 50176);             // 50176
    int*   row_start  = (int*)(ws + 100352);            // 50432 (N+1)
    int*   epos       = (int*)(ws + 150784);            // 600064
    float* W4p        = ws + 750912;                    // 256
    float* b4p        = ws + 751168;                    // 64 (2 used)
    int*   src_sorted = (int*)(ws + 751232);            // 600064
    float* P3s        = ws + 1351296;                   // N*2 (pad 100352)
    float* Xs         = ws + 1451648;                   // N*4
    unsigned short* Hbuf16 = (unsigned short*)(ws + 1652352);         // NPAD*128 bf16 (layer-2 H)
    unsigned short* H3buf  = (unsigned short*)(ws + 1652352 + (size_t)NPAD * 64);  // layer-3 H
    unsigned short* Wt2g   = (unsigned short*)(ws + 1652352 + 2 * (size_t)NPAD * 64);
    unsigned short* Wt3g   = Wt2g + HID * HID;          // 16384 bf16 each

    const int B = 256;

    // --- Setup ---
    k_setup1<<<NB1024 + 3, 1024, 0, stream>>>(deg_i, N, NB1024, W4, linW, b4, linb,
                                              W4p, b4p, W2, W3, Wt2g, Wt3g);
    k_count<<<(E + B - 1) / B, B, 0, stream>>>(ei, deg_i, epos, E);
    k_scan2b<<<NB1024, 1024, 0, stream>>>(deg_i, row_start, dinv, x, Xs, N, NB1024);
    k_fill<<<(E + B - 1) / B, B, 0, stream>>>(ei, row_start, epos, src_sorted, E);

    const int gatherBlocks = (N + 15) / 16;    // 4 nodes/wave, 4 waves/block
    const int gemmBlocks   = NPAD / 64;

    // --- Layer 1 + GEMM2 fused -> Hbuf16 ---
    k_l1g2<<<gemmBlocks, B, 0, stream>>>(Xs, row_start, src_sorted, dinv, W1, b1,
                                         Wt2g, Hbuf16, N);
    // --- Layer 2 aggregation + GEMM3 fused -> H3buf (NOT in-place on Hbuf16) ---
    k_gagm<<<gemmBlocks, B, 0, stream>>>(Hbuf16, row_start, src_sorted, dinv, b2,
                                         Wt3g, H3buf, N);
    // --- Layer 3 aggregation + W4p projection -> P3s ---
    k_gather_proj<<<gatherBlocks, B, 0, stream>>>(H3buf, row_start, src_sorted, dinv, b3, W4p, P3s, N);
    // --- Layer 4 + pool + head ---
    k_tail<<<NGRAPH, B, 0, stream>>>(P3s, row_start, src_sorted, dinv, batch, b4p, out, N);
}